// Round 12
// baseline (31.158 us; speedup 1.0000x reference)
//
#include <hip/hip_runtime.h>
#include <math.h>

#define NB 4
#define NN 512
#define ND 128
#define NC 10
#define NT 32                // 16-wide tiles per side
#define NBLK_M (NB*NT*8)     // 1024 blocks: (b, Tj, q); q = quartet of i-tiles

typedef short    bf16x8 __attribute__((ext_vector_type(8)));
typedef unsigned u32x4  __attribute__((ext_vector_type(4)));
typedef float    f32x4  __attribute__((ext_vector_type(4)));

// pack two f32 into two truncated bf16 (low short = a, high short = b)
static __device__ __forceinline__ unsigned pack_trunc(float a, float b) {
    unsigned ua = __builtin_bit_cast(unsigned, a);
    unsigned ub = __builtin_bit_cast(unsigned, b);
    return (ua >> 16) | (ub & 0xFFFF0000u);
}

// Fused: build MFMA fragments in-register from x and W, 16x16x32 bf16 MFMA
// (bf16x2 split: ah*bh + al*bh), fused softmax/focal epilogue.
// Frag semantics (r9/r10/r11-verified):
//   A-frag (g): lane l holds x[row = Ti*16 + (l&15)][d = 32g + 8*(l>>4) + e], e=0..7
//   B-frag (c,g): lane l holds y_c[col = Tj*16 + (l&15)][same d-enumeration]
//   C/D: col = lane&15, row = (lane>>4)*4 + reg
__global__ __launch_bounds__(256) void w2ner_fused(
    const float* __restrict__ x, const int* __restrict__ span,
    const int* __restrict__ seqlen, const float* __restrict__ Wm,
    const float* __restrict__ bias, float* __restrict__ out,
    float* __restrict__ accum)
{
    __shared__ float sRed[4 * 5];
    const int tid = threadIdx.x;
    // XCD co-location: the 8 blocks sharing (b,Tj) get consecutive logical ids
    const int lb = (blockIdx.x & 7) * (NBLK_M / 8) + (blockIdx.x >> 3);
    const int q  = lb & 7;
    const int Tj = (lb >> 3) & 31;
    const int b  = lb >> 8;
    const int wv = tid >> 6, l = tid & 63;
    const int jl = l & 15, kg = l >> 4;       // kg doubles as C/D row-group
    const int Ti = q * 4 + wv;                // this wave's i-tile
    const int j  = Tj * 16 + jl;
    const int sl = seqlen[b];
    const float* xb = x + (size_t)b * NN * ND;
    const int irow = Ti * 16 + jl;

    // ---- prefetch: all x chunks (16 float4) + span (4 dwords) up front ----
    float xi[4][8], xj[4][8];
    #pragma unroll
    for (int g = 0; g < 4; ++g) {
        const int d0 = 32 * g + 8 * kg;
        *(float4*)&xi[g][0] = *(const float4*)(xb + (size_t)irow * ND + d0);
        *(float4*)&xi[g][4] = *(const float4*)(xb + (size_t)irow * ND + d0 + 4);
        *(float4*)&xj[g][0] = *(const float4*)(xb + (size_t)j * ND + d0);
        *(float4*)&xj[g][4] = *(const float4*)(xb + (size_t)j * ND + d0 + 4);
    }
    const int ib = Ti * 16 + kg * 4;
    int sp[4];
    #pragma unroll
    for (int r = 0; r < 4; ++r)
        sp[r] = span[(size_t)b * NN * NN + (size_t)(ib + r) * NN + j];

    f32x4 acc[NC];
    #pragma unroll
    for (int c = 0; c < NC; ++c) acc[c] = (f32x4){0.f, 0.f, 0.f, 0.f};

    #pragma unroll
    for (int g = 0; g < 4; ++g) {
        const int d0 = 32 * g + 8 * kg;

        // A fragment: exact hi/lo split (truncation; x == hi + lo to 2^-16)
        u32x4 ahw, alw;
        #pragma unroll
        for (int e2 = 0; e2 < 4; ++e2) {
            const float a0 = xi[g][2 * e2], a1 = xi[g][2 * e2 + 1];
            const unsigned u0 = __builtin_bit_cast(unsigned, a0) & 0xFFFF0000u;
            const unsigned u1 = __builtin_bit_cast(unsigned, a1) & 0xFFFF0000u;
            const float h0 = __builtin_bit_cast(float, u0);
            const float h1 = __builtin_bit_cast(float, u1);
            ahw[e2] = (u0 >> 16) | u1;
            alw[e2] = pack_trunc(a0 - h0, a1 - h1);
        }

        // B fragments (one per class): y = x_j * W, rounded once to bf16 (trunc)
        u32x4 yw[NC];
        #pragma unroll
        for (int e2 = 0; e2 < 4; ++e2) {
            // W rows d0+2e2, d0+2e2+1: 20 contiguous floats, 16B-aligned
            float wb[20];
            const float4* wp = (const float4*)(Wm + (size_t)(d0 + 2 * e2) * NC);
            #pragma unroll
            for (int t5 = 0; t5 < 5; ++t5) *(float4*)&wb[4 * t5] = wp[t5];
            const float x0 = xj[g][2 * e2], x1 = xj[g][2 * e2 + 1];
            #pragma unroll
            for (int c = 0; c < NC; ++c)
                yw[c][e2] = pack_trunc(x0 * wb[c], x1 * wb[10 + c]);
        }

        // MFMAs: 2 per class (hi + lo correction)
        const bf16x8 ah = __builtin_bit_cast(bf16x8, ahw);
        const bf16x8 al = __builtin_bit_cast(bf16x8, alw);
        #pragma unroll
        for (int c = 0; c < NC; ++c) {
            const bf16x8 bh = __builtin_bit_cast(bf16x8, yw[c]);
            acc[c] = __builtin_amdgcn_mfma_f32_16x16x32_bf16(ah, bh, acc[c], 0, 0, 0);
            acc[c] = __builtin_amdgcn_mfma_f32_16x16x32_bf16(al, bh, acc[c], 0, 0, 0);
        }
    }

    float lsum = 0.f, accn = 0.f, tpn = 0.f, tnn = 0.f, fpn = 0.f;
    #pragma unroll
    for (int r = 0; r < 4; ++r) {
        const int i = ib + r;
        float L[NC];
        #pragma unroll
        for (int c = 0; c < NC; ++c) L[c] = acc[c][r] + bias[c];
        int am = 0; float mx = L[0];
        #pragma unroll
        for (int c = 1; c < NC; ++c) { if (L[c] > mx) { mx = L[c]; am = c; } }  // first-occurrence argmax
        float e[NC]; float s = 0.f;
        #pragma unroll
        for (int c = 0; c < NC; ++c) { e[c] = __expf(L[c] - mx); s += e[c]; }
        const int spv = sp[r];
        float lsp = L[0], esp = e[0];
        #pragma unroll
        for (int c = 1; c < NC; ++c) {
            lsp = (spv == c) ? L[c] : lsp;
            esp = (spv == c) ? e[c] : esp;
        }
        const float inv  = __builtin_amdgcn_rcpf(s);
        const float lp   = (lsp - mx) - __logf(s);
        const float prob = esp * inv;
        const float om   = 1.f - prob;
        const float lm   = -(om * om) * lp;
        const bool v = (i < sl) && (j < sl);
        const int pred = v ? am : 0;
        out[(size_t)b * NN * NN + (size_t)i * NN + j] = (float)pred;
        if (v) { lsum += lm; if (pred == spv) accn += 1.f; }
        if (spv > 0) { if (pred == spv) tpn += 1.f; else tnn += 1.f; }
        else if (pred > 0 && v) fpn += 1.f;
    }

    float vals[5] = { lsum, accn, tpn, tnn, fpn };
    #pragma unroll
    for (int k = 0; k < 5; ++k) {
        float vv = vals[k];
        for (int o = 32; o > 0; o >>= 1) vv += __shfl_down(vv, o);
        vals[k] = vv;
    }
    if (l == 0) {
        #pragma unroll
        for (int k = 0; k < 5; ++k) sRed[wv * 5 + k] = vals[k];
    }
    __syncthreads();
    if (tid < 5) {
        float t = sRed[tid] + sRed[5 + tid] + sRed[10 + tid] + sRed[15 + tid];
        accum[(size_t)blockIdx.x * 5 + tid] = t;
    }
}

__global__ __launch_bounds__(256) void w2ner_final(
    const int* __restrict__ seqlen, const float* __restrict__ accum,
    float* __restrict__ out)
{
    __shared__ float sP[4][5];
    const int tid = threadIdx.x;
    float part[5] = {0.f, 0.f, 0.f, 0.f, 0.f};
    for (int r = tid; r < NBLK_M; r += 256) {
        #pragma unroll
        for (int k = 0; k < 5; ++k) part[k] += accum[(size_t)r * 5 + k];
    }
    #pragma unroll
    for (int k = 0; k < 5; ++k) {
        float v = part[k];
        for (int o = 32; o > 0; o >>= 1) v += __shfl_down(v, o);
        part[k] = v;
    }
    const int wave = tid >> 6;
    const int lane = tid & 63;
    if (lane == 0) {
        #pragma unroll
        for (int k = 0; k < 5; ++k) sP[wave][k] = part[k];
    }
    __syncthreads();
    if (tid == 0) {
        float t[5];
        #pragma unroll
        for (int k = 0; k < 5; ++k) t[k] = sP[0][k] + sP[1][k] + sP[2][k] + sP[3][k];
        float s2 = 0.f;
        for (int k = 0; k < NB; ++k) { float s = (float)seqlen[k]; s2 += s * s; }
        const size_t base = (size_t)NB * NN * NN;
        out[base + 0] = t[2];          // tp
        out[base + 1] = t[3];          // tn
        out[base + 2] = t[4];          // fp
        out[base + 3] = t[0] / s2;     // loss
        out[base + 4] = t[1] / s2;     // accuracy
    }
}

extern "C" void kernel_launch(void* const* d_in, const int* in_sizes, int n_in,
                              void* d_out, int out_size, void* d_ws, size_t ws_size,
                              hipStream_t stream) {
    const float* x      = (const float*)d_in[0];
    const int*   span   = (const int*)d_in[1];
    const int*   seqlen = (const int*)d_in[2];
    const float* Wm     = (const float*)d_in[3];
    const float* bias   = (const float*)d_in[4];
    float* out   = (float*)d_out;
    float* accum = (float*)d_ws;   // 1024*5 f32, fully overwritten each launch

    w2ner_fused<<<dim3(NBLK_M), 256, 0, stream>>>(x, span, seqlen, Wm, bias, out, accum);
    w2ner_final<<<1, 256, 0, stream>>>(seqlen, accum, out);
}

// Round 13
// 23.896 us; speedup vs baseline: 1.3039x; 1.3039x over previous
//
#include <hip/hip_runtime.h>
#include <math.h>

#define NB 4
#define NN 512
#define ND 128
#define NC 10
#define NT 32                // 16-wide tiles per side
#define MREP 2               // i-tiles per wave
#define NBLK_M (NB*NT*4)     // 512 blocks: (b, Tj, q); q = octet of i-tiles

typedef short    bf16x8 __attribute__((ext_vector_type(8)));
typedef unsigned u32x4  __attribute__((ext_vector_type(4)));
typedef float    f32x4  __attribute__((ext_vector_type(4)));

// pack two f32 into two truncated bf16 (low short = a, high short = b)
static __device__ __forceinline__ unsigned pack_trunc(float a, float b) {
    unsigned ua = __builtin_bit_cast(unsigned, a);
    unsigned ub = __builtin_bit_cast(unsigned, b);
    return (ua >> 16) | (ub & 0xFFFF0000u);
}

// Fused MFMA kernel with block-shared B-fragments.
// Frag semantics (r9-r12 verified, absmax 256 vs thr 17694):
//   A-frag (g): lane l holds x[row = Ti*16 + (l&15)][d = 32g + 8*(l>>4) + e], e=0..7
//   B-frag (c,g): lane l holds y_c[col = Tj*16 + (l&15)][same d-enumeration]
//   C/D: col = lane&15, row = (lane>>4)*4 + reg
// B-set (40 frags, 40KB) is built ONCE per block (wave wv builds g=wv) and
// shared via LDS -- removes the 4x-duplicated W-load + pack chain from waves.
__global__ __launch_bounds__(256) void w2ner_fused(
    const float* __restrict__ x, const int* __restrict__ span,
    const int* __restrict__ seqlen, const float* __restrict__ Wm,
    const float* __restrict__ bias, float* __restrict__ out,
    float* __restrict__ accum)
{
    __shared__ u32x4 sB[40 * 64];     // [ (g*10+c) * 64 + lane ]  = 40 KB
    __shared__ float sRed[4 * 5];

    const int tid = threadIdx.x;
    const int blk = blockIdx.x;
    const int q  = blk & 3;
    const int Tj = (blk >> 2) & 31;
    const int b  = blk >> 7;
    const int wv = tid >> 6, l = tid & 63;
    const int jl = l & 15, kg = l >> 4;       // kg doubles as C/D row-group
    const int Ti0 = q * 8 + wv * MREP;
    const int j  = Tj * 16 + jl;
    const int sl = seqlen[b];
    const float* xb = x + (size_t)b * NN * ND;

    // ---- span prefetch (8 scattered loads; hidden under B-build + GEMM) ----
    int sp[MREP][4];
    #pragma unroll
    for (int m = 0; m < MREP; ++m) {
        const int ib = (Ti0 + m) * 16 + kg * 4;
        #pragma unroll
        for (int r = 0; r < 4; ++r)
            sp[m][r] = span[(size_t)b * NN * NN + (size_t)(ib + r) * NN + j];
    }

    // ---- Phase 0: wave wv builds B-frags for g = wv (all 10 classes) ----
    {
        const int d0w = 32 * wv + 8 * kg;
        float xjv[8];
        *(float4*)&xjv[0] = *(const float4*)(xb + (size_t)j * ND + d0w);
        *(float4*)&xjv[4] = *(const float4*)(xb + (size_t)j * ND + d0w + 4);
        u32x4 yw[NC];
        #pragma unroll
        for (int e2 = 0; e2 < 4; ++e2) {
            float wb[20];   // W rows d0w+2e2, d0w+2e2+1 (20 contiguous floats)
            const float4* wp = (const float4*)(Wm + (size_t)(d0w + 2 * e2) * NC);
            #pragma unroll
            for (int t5 = 0; t5 < 5; ++t5) *(float4*)&wb[4 * t5] = wp[t5];
            const float x0 = xjv[2 * e2], x1 = xjv[2 * e2 + 1];
            #pragma unroll
            for (int c = 0; c < NC; ++c)
                yw[c][e2] = pack_trunc(x0 * wb[c], x1 * wb[10 + c]);
        }
        #pragma unroll
        for (int c = 0; c < NC; ++c)
            sB[(wv * NC + c) * 64 + l] = yw[c];
    }
    __syncthreads();

    // ---- Phase 1: GEMM. A built in-register per g; B read from LDS ----
    f32x4 acc[MREP][NC];
    #pragma unroll
    for (int m = 0; m < MREP; ++m)
        #pragma unroll
        for (int c = 0; c < NC; ++c) acc[m][c] = (f32x4){0.f, 0.f, 0.f, 0.f};

    #pragma unroll
    for (int g = 0; g < 4; ++g) {
        const int d0 = 32 * g + 8 * kg;
        bf16x8 ah[MREP], al[MREP];
        #pragma unroll
        for (int m = 0; m < MREP; ++m) {
            const int irow = (Ti0 + m) * 16 + jl;
            float xiv[8];
            *(float4*)&xiv[0] = *(const float4*)(xb + (size_t)irow * ND + d0);
            *(float4*)&xiv[4] = *(const float4*)(xb + (size_t)irow * ND + d0 + 4);
            u32x4 ahw, alw;
            #pragma unroll
            for (int e2 = 0; e2 < 4; ++e2) {
                const float a0 = xiv[2 * e2], a1 = xiv[2 * e2 + 1];
                const unsigned u0 = __builtin_bit_cast(unsigned, a0) & 0xFFFF0000u;
                const unsigned u1 = __builtin_bit_cast(unsigned, a1) & 0xFFFF0000u;
                const float h0 = __builtin_bit_cast(float, u0);
                const float h1 = __builtin_bit_cast(float, u1);
                ahw[e2] = (u0 >> 16) | u1;
                alw[e2] = pack_trunc(a0 - h0, a1 - h1);
            }
            ah[m] = __builtin_bit_cast(bf16x8, ahw);
            al[m] = __builtin_bit_cast(bf16x8, alw);
        }
        #pragma unroll
        for (int c = 0; c < NC; ++c) {
            const bf16x8 bh = __builtin_bit_cast(bf16x8, sB[(g * NC + c) * 64 + l]);
            #pragma unroll
            for (int m = 0; m < MREP; ++m) {
                acc[m][c] = __builtin_amdgcn_mfma_f32_16x16x32_bf16(ah[m], bh, acc[m][c], 0, 0, 0);
                acc[m][c] = __builtin_amdgcn_mfma_f32_16x16x32_bf16(al[m], bh, acc[m][c], 0, 0, 0);
            }
        }
    }

    // ---- Phase 2: fused softmax/focal epilogue (unchanged from r11) ----
    float lsum = 0.f, accn = 0.f, tpn = 0.f, tnn = 0.f, fpn = 0.f;
    #pragma unroll
    for (int m = 0; m < MREP; ++m) {
        const int ib = (Ti0 + m) * 16 + kg * 4;   // C/D rows: (lane>>4)*4 + reg
        #pragma unroll
        for (int r = 0; r < 4; ++r) {
            const int i = ib + r;
            float L[NC];
            #pragma unroll
            for (int c = 0; c < NC; ++c) L[c] = acc[m][c][r] + bias[c];
            int am = 0; float mx = L[0];
            #pragma unroll
            for (int c = 1; c < NC; ++c) { if (L[c] > mx) { mx = L[c]; am = c; } }  // first-occurrence argmax
            float e[NC]; float s = 0.f;
            #pragma unroll
            for (int c = 0; c < NC; ++c) { e[c] = __expf(L[c] - mx); s += e[c]; }
            const int spv = sp[m][r];
            float lsp = L[0], esp = e[0];
            #pragma unroll
            for (int c = 1; c < NC; ++c) {
                lsp = (spv == c) ? L[c] : lsp;
                esp = (spv == c) ? e[c] : esp;
            }
            const float inv  = __builtin_amdgcn_rcpf(s);
            const float lp   = (lsp - mx) - __logf(s);
            const float prob = esp * inv;
            const float om   = 1.f - prob;
            const float lm   = -(om * om) * lp;
            const bool v = (i < sl) && (j < sl);
            const int pred = v ? am : 0;
            out[(size_t)b * NN * NN + (size_t)i * NN + j] = (float)pred;
            if (v) { lsum += lm; if (pred == spv) accn += 1.f; }
            if (spv > 0) { if (pred == spv) tpn += 1.f; else tnn += 1.f; }
            else if (pred > 0 && v) fpn += 1.f;
        }
    }

    float vals[5] = { lsum, accn, tpn, tnn, fpn };
    #pragma unroll
    for (int k = 0; k < 5; ++k) {
        float vv = vals[k];
        for (int o = 32; o > 0; o >>= 1) vv += __shfl_down(vv, o);
        vals[k] = vv;
    }
    if (l == 0) {
        #pragma unroll
        for (int k = 0; k < 5; ++k) sRed[wv * 5 + k] = vals[k];
    }
    __syncthreads();
    if (tid < 5) {
        float t = sRed[tid] + sRed[5 + tid] + sRed[10 + tid] + sRed[15 + tid];
        accum[(size_t)blk * 5 + tid] = t;
    }
}

__global__ __launch_bounds__(256) void w2ner_final(
    const int* __restrict__ seqlen, const float* __restrict__ accum,
    float* __restrict__ out)
{
    __shared__ float sP[4][5];
    const int tid = threadIdx.x;
    float part[5] = {0.f, 0.f, 0.f, 0.f, 0.f};
    for (int r = tid; r < NBLK_M; r += 256) {
        #pragma unroll
        for (int k = 0; k < 5; ++k) part[k] += accum[(size_t)r * 5 + k];
    }
    #pragma unroll
    for (int k = 0; k < 5; ++k) {
        float v = part[k];
        for (int o = 32; o > 0; o >>= 1) v += __shfl_down(v, o);
        part[k] = v;
    }
    const int wave = tid >> 6;
    const int lane = tid & 63;
    if (lane == 0) {
        #pragma unroll
        for (int k = 0; k < 5; ++k) sP[wave][k] = part[k];
    }
    __syncthreads();
    if (tid == 0) {
        float t[5];
        #pragma unroll
        for (int k = 0; k < 5; ++k) t[k] = sP[0][k] + sP[1][k] + sP[2][k] + sP[3][k];
        float s2 = 0.f;
        for (int k = 0; k < NB; ++k) { float s = (float)seqlen[k]; s2 += s * s; }
        const size_t base = (size_t)NB * NN * NN;
        out[base + 0] = t[2];          // tp
        out[base + 1] = t[3];          // tn
        out[base + 2] = t[4];          // fp
        out[base + 3] = t[0] / s2;     // loss
        out[base + 4] = t[1] / s2;     // accuracy
    }
}

extern "C" void kernel_launch(void* const* d_in, const int* in_sizes, int n_in,
                              void* d_out, int out_size, void* d_ws, size_t ws_size,
                              hipStream_t stream) {
    const float* x      = (const float*)d_in[0];
    const int*   span   = (const int*)d_in[1];
    const int*   seqlen = (const int*)d_in[2];
    const float* Wm     = (const float*)d_in[3];
    const float* bias   = (const float*)d_in[4];
    float* out   = (float*)d_out;
    float* accum = (float*)d_ws;   // 512*5 f32, fully overwritten each launch

    w2ner_fused<<<dim3(NBLK_M), 256, 0, stream>>>(x, span, seqlen, Wm, bias, out, accum);
    w2ner_final<<<1, 256, 0, stream>>>(seqlen, accum, out);
}